// Round 5
// baseline (160.758 us; speedup 1.0000x reference)
//
#include <hip/hip_runtime.h>

// MultiHeadFullAttention: B=2, T=2048, D=1024, H=16, dh=64, causal.
// fp32->bf16 cvt (2 launches) -> fused QKV GEMM (m97-style 4-wave MFMA, LDS dbuf;
// 1/8 scale folded into Q) -> flash attn (512 thr, 2 q-tiles/block, defer-max)
// -> output GEMM (BN=64 for 2 blocks/CU).

typedef __attribute__((ext_vector_type(8))) __bf16 bf16x8;
typedef __attribute__((ext_vector_type(4))) float f32x4;
typedef unsigned short u16;

constexpr int BATCH  = 2;
constexpr int TSEQ   = 2048;
constexpr int DMODEL = 1024;
constexpr int NHEAD  = 16;
constexpr int DHEAD  = 64;
constexpr int MROWS  = BATCH * TSEQ;  // 4096

static __device__ __forceinline__ u16 f2bf(float f) {
  union { float f; unsigned int u; } v; v.f = f;
  unsigned int u = v.u;
  return (u16)((u + 0x7fffu + ((u >> 16) & 1u)) >> 16);
}

// async global->LDS, 16B per lane; lds base must be wave-uniform (HW adds lane*16)
static __device__ __forceinline__ void gload16(const void* g, void* l) {
  __builtin_amdgcn_global_load_lds(
      (const __attribute__((address_space(1))) void*)g,
      (__attribute__((address_space(3))) void*)l, 16, 0, 0);
}

__global__ __launch_bounds__(256) void cvt_multi(const float* __restrict__ s0,
                                                 const float* __restrict__ s1,
                                                 const float* __restrict__ s2,
                                                 const float* __restrict__ s3,
                                                 u16* __restrict__ d0, u16* __restrict__ d1,
                                                 u16* __restrict__ d2, u16* __restrict__ d3,
                                                 int n4) {
  const float* s; u16* d;
  switch (blockIdx.y) {
    case 0: s = s0; d = d0; break;
    case 1: s = s1; d = d1; break;
    case 2: s = s2; d = d2; break;
    default: s = s3; d = d3; break;
  }
  int i = blockIdx.x * 256 + threadIdx.x;
  if (i >= n4) return;
  float4 f = ((const float4*)s)[i];
  ushort4 o;
  o.x = f2bf(f.x); o.y = f2bf(f.y); o.z = f2bf(f.z); o.w = f2bf(f.w);
  ((ushort4*)d)[i] = o;
}

// ------------- GEMM core: C[m][n] = X[m][:] . W[n][:] + bias[n] -------------
// m97-style: 256 thr = 4 waves (2x2), tile 128 x BN, BK=32, dbuf LDS,
// 4x(BN/32) fragments per wave = 16 (BN=128) MFMA per wave per barrier.
// LDS fragment order: site s = row>>4; byte(row,k8) = s*1024 + (k8&3)*256 +
// (row&15)*16 -> ds_read_b128 at site*1024 + lane*16 (conflict-free) and the
// gload_lds dest is linear per site.
template <int BN, typename Epi>
static __device__ __forceinline__ void gemm_body(const u16* __restrict__ X_,
                                                 const u16* __restrict__ W_,
                                                 const float* __restrict__ bias,
                                                 Epi epi) {
  constexpr int K = DMODEL;
  constexpr int NT = BN / 32;  // fragments per wave in N
  __shared__ __align__(16) u16 As[2][8 * 512];
  __shared__ __align__(16) u16 Bs[2][(BN / 16) * 512];
  const int lane = threadIdx.x & 63, wave = threadIdx.x >> 6;
  const int l16 = lane & 15, lk = lane >> 4;
  const int wm = wave >> 1, wn = wave & 1;
  const int row0 = blockIdx.x * 128, col0 = blockIdx.y * BN;

  const u16* ga = X_ + (size_t)(row0 + l16) * K + lk * 8;
  const u16* gb = W_ + (size_t)(col0 + l16) * K + lk * 8;

  f32x4 acc[4][NT];
#pragma unroll
  for (int mt = 0; mt < 4; ++mt)
#pragma unroll
    for (int nt = 0; nt < NT; ++nt) acc[mt][nt] = (f32x4){0.f, 0.f, 0.f, 0.f};

  auto stage = [&](int bufi, int ks) {
#pragma unroll
    for (int j = 0; j < 2; ++j) {  // A: 8 sites / 4 waves
      int s = j * 4 + wave;
      gload16(ga + (size_t)s * 16 * K + ks * 32, &As[bufi][s * 512]);
    }
#pragma unroll
    for (int j = 0; j < BN / 64; ++j) {  // B: BN/16 sites / 4 waves
      int s = j * 4 + wave;
      gload16(gb + (size_t)s * 16 * K + ks * 32, &Bs[bufi][s * 512]);
    }
  };

  stage(0, 0);
  __syncthreads();
  int buf = 0;
  for (int ks = 0; ks < K / 32; ++ks) {
    if (ks + 1 < K / 32) stage(buf ^ 1, ks + 1);
    bf16x8 a[4], b[NT];
#pragma unroll
    for (int mt = 0; mt < 4; ++mt)
      a[mt] = *(const bf16x8*)&As[buf][(wm * 4 + mt) * 512 + lane * 8];
#pragma unroll
    for (int nt = 0; nt < NT; ++nt)
      b[nt] = *(const bf16x8*)&Bs[buf][(wn * NT + nt) * 512 + lane * 8];
#pragma unroll
    for (int mt = 0; mt < 4; ++mt)
#pragma unroll
      for (int nt = 0; nt < NT; ++nt)
        acc[mt][nt] =
            __builtin_amdgcn_mfma_f32_16x16x32_bf16(a[mt], b[nt], acc[mt][nt], 0, 0, 0);
    __syncthreads();
    buf ^= 1;
  }
#pragma unroll
  for (int mt = 0; mt < 4; ++mt)
#pragma unroll
    for (int nt = 0; nt < NT; ++nt)
#pragma unroll
      for (int r = 0; r < 4; ++r) {
        int m = row0 + wm * 64 + mt * 16 + lk * 4 + r;
        int n = col0 + wn * (BN / 2) + nt * 16 + l16;
        float v = acc[mt][nt][r] + bias[n];
        epi(m, n, v);
      }
}

// z: 0=Q (scaled by 1/8), 1=K (both -> [B,H,T,dh]), 2=V (-> [B,H,dh,T])
__global__ __launch_bounds__(256, 4) void gemm_qkv(
    const u16* __restrict__ xq, const u16* __restrict__ xk, const u16* __restrict__ xv,
    const u16* __restrict__ wq, const u16* __restrict__ wk, const u16* __restrict__ wv,
    const float* __restrict__ bq, const float* __restrict__ bk, const float* __restrict__ bv,
    u16* __restrict__ Qh, u16* __restrict__ Kh, u16* __restrict__ Vt) {
  const int z = blockIdx.z;
  const u16* X = z == 0 ? xq : (z == 1 ? xk : xv);
  const u16* W = z == 0 ? wq : (z == 1 ? wk : wv);
  const float* bias = z == 0 ? bq : (z == 1 ? bk : bv);
  u16* O01 = z == 0 ? Qh : Kh;
  gemm_body<128>(X, W, bias, [&](int m, int n, float v) {
    int bb = m >> 11, t = m & (TSEQ - 1);
    int h = n >> 6, dd = n & (DHEAD - 1);
    if (z == 0) v *= 0.125f;  // fold 1/sqrt(dh) into Q
    if (z == 2)
      Vt[(((size_t)(bb * NHEAD + h)) * DHEAD + dd) * TSEQ + t] = f2bf(v);
    else
      O01[(((size_t)(bb * NHEAD + h)) * TSEQ + t) * DHEAD + dd] = f2bf(v);
  });
}

__global__ __launch_bounds__(256, 4) void gemm_o(const u16* __restrict__ AO,
                                                 const u16* __restrict__ wo,
                                                 const float* __restrict__ bias,
                                                 float* __restrict__ out) {
  gemm_body<64>(AO, wo, bias,
                [&](int m, int n, float v) { out[(size_t)m * DMODEL + n] = v; });
}

// ---------------- flash attention (unchanged from r4) ----------------
__global__ __launch_bounds__(512, 6) void flash_attn(const u16* __restrict__ Qh,
                                                     const u16* __restrict__ Kh,
                                                     const u16* __restrict__ Vt,
                                                     u16* __restrict__ AO) {
  const int lane = threadIdx.x & 63, wave = threadIdx.x >> 6;
  const int l16 = lane & 15, lk = lane >> 4;
  const int bh = blockIdx.x;
  const int qt = (gridDim.y - 1) - blockIdx.y;  // heavy-first
  const int q0 = qt * 128;
  const int b = bh >> 4, h = bh & 15;

  __shared__ __align__(16) u16 Kl[2][4096];
  __shared__ __align__(16) u16 Vl[2][4096];
  __shared__ __align__(16) u16 plds[8][16][72];

  const u16* Qb = Qh + (size_t)bh * TSEQ * DHEAD;
  const u16* Kb = Kh + (size_t)bh * TSEQ * DHEAD;
  const u16* Vb = Vt + (size_t)bh * DHEAD * TSEQ;

  bf16x8 qf[2];
  {
    const u16* qp = Qb + (size_t)(q0 + wave * 16 + l16) * DHEAD + lk * 8;
    qf[0] = *(const bf16x8*)(qp);
    qf[1] = *(const bf16x8*)(qp + 32);
  }

  float mrow[4], lsum[4];
  f32x4 acco[4];
#pragma unroll
  for (int r = 0; r < 4; ++r) { mrow[r] = -1e30f; lsum[r] = 0.f; }
#pragma unroll
  for (int dt = 0; dt < 4; ++dt) acco[dt] = (f32x4){0.f, 0.f, 0.f, 0.f};

  auto stage_kv = [&](int bufi, int kbase) {
    int trow = (wave >> 1) * 16 + l16;
    int dhs = (wave & 1) * 4 + lk;
    gload16(Kb + (size_t)(kbase + trow) * DHEAD + dhs * 8, &Kl[bufi][wave * 512]);
    gload16(Vb + (size_t)trow * TSEQ + kbase + dhs * 8, &Vl[bufi][wave * 512]);
  };

  const int nkb = 2 * qt + 2;
  const int kbdiag = 2 * qt + (wave >> 2);  // this wave's diagonal K-block
  stage_kv(0, 0);
  __syncthreads();
  int buf = 0;
  const int qrow_base = q0 + wave * 16 + 4 * lk;

  for (int kb = 0; kb < nkb; ++kb) {
    const int kbase = kb * 64;
    if (kb + 1 < nkb) stage_kv(buf ^ 1, kbase + 64);

    if (kb <= kbdiag) {
      f32x4 s[4];
#pragma unroll
      for (int nt = 0; nt < 4; ++nt) {
        bf16x8 k0f = *(const bf16x8*)&Kl[buf][nt * 1024 + lane * 8];
        bf16x8 k1f = *(const bf16x8*)&Kl[buf][nt * 1024 + 512 + lane * 8];
        f32x4 z = (f32x4){0.f, 0.f, 0.f, 0.f};
        z = __builtin_amdgcn_mfma_f32_16x16x32_bf16(qf[0], k0f, z, 0, 0, 0);
        z = __builtin_amdgcn_mfma_f32_16x16x32_bf16(qf[1], k1f, z, 0, 0, 0);
        s[nt] = z;
      }
      if (kb == kbdiag) {  // only the diagonal block needs masking
#pragma unroll
        for (int nt = 0; nt < 4; ++nt)
#pragma unroll
          for (int r = 0; r < 4; ++r) {
            int kcol = kbase + nt * 16 + l16;
            s[nt][r] = (kcol <= qrow_base + r) ? s[nt][r] : -1e30f;
          }
      }
      float pmax[4];
      bool need = false;
#pragma unroll
      for (int r = 0; r < 4; ++r) {
        pmax[r] = fmaxf(fmaxf(s[0][r], s[1][r]), fmaxf(s[2][r], s[3][r]));
        need |= (pmax[r] > mrow[r] + 8.f);
      }
      if (__any(need)) {
#pragma unroll
        for (int r = 0; r < 4; ++r) {
          float mx = pmax[r];
#pragma unroll
          for (int off = 1; off < 16; off <<= 1) mx = fmaxf(mx, __shfl_xor(mx, off, 16));
          float mnew = fmaxf(mrow[r], mx);
          float alpha = __expf(mrow[r] - mnew);
          lsum[r] *= alpha;
#pragma unroll
          for (int dt = 0; dt < 4; ++dt) acco[dt][r] *= alpha;
          mrow[r] = mnew;
        }
      }
#pragma unroll
      for (int r = 0; r < 4; ++r)
#pragma unroll
        for (int nt = 0; nt < 4; ++nt) {
          float p = __expf(s[nt][r] - mrow[r]);
          s[nt][r] = p;
          lsum[r] += p;
        }
#pragma unroll
      for (int nt = 0; nt < 4; ++nt)
#pragma unroll
        for (int r = 0; r < 4; ++r)
          plds[wave][4 * lk + r][nt * 16 + l16] = f2bf(s[nt][r]);
      bf16x8 pf0 = *(const bf16x8*)&plds[wave][l16][lk * 8];
      bf16x8 pf1 = *(const bf16x8*)&plds[wave][l16][32 + lk * 8];
#pragma unroll
      for (int dt = 0; dt < 4; ++dt) {
        bf16x8 v0 = *(const bf16x8*)&Vl[buf][dt * 1024 + lane * 8];
        bf16x8 v1 = *(const bf16x8*)&Vl[buf][dt * 1024 + 512 + lane * 8];
        acco[dt] = __builtin_amdgcn_mfma_f32_16x16x32_bf16(pf0, v0, acco[dt], 0, 0, 0);
        acco[dt] = __builtin_amdgcn_mfma_f32_16x16x32_bf16(pf1, v1, acco[dt], 0, 0, 0);
      }
    }
    __syncthreads();
    buf ^= 1;
  }

#pragma unroll
  for (int r = 0; r < 4; ++r) {
    float t = lsum[r];
#pragma unroll
    for (int off = 1; off < 16; off <<= 1) t += __shfl_xor(t, off, 16);
    lsum[r] = 1.f / t;
  }
#pragma unroll
  for (int dt = 0; dt < 4; ++dt)
#pragma unroll
    for (int r = 0; r < 4; ++r) {
      int t = qrow_base + r;
      int col = h * DHEAD + dt * 16 + l16;
      AO[((size_t)(b * TSEQ + t)) * DMODEL + col] = f2bf(acco[dt][r] * lsum[r]);
    }
}

extern "C" void kernel_launch(void* const* d_in, const int* in_sizes, int n_in,
                              void* d_out, int out_size, void* d_ws, size_t ws_size,
                              hipStream_t stream) {
  const float* x_q = (const float*)d_in[0];
  const float* x_k = (const float*)d_in[1];
  const float* x_v = (const float*)d_in[2];
  const float* Wq = (const float*)d_in[4];
  const float* bq = (const float*)d_in[5];
  const float* Wk = (const float*)d_in[6];
  const float* bk = (const float*)d_in[7];
  const float* Wv = (const float*)d_in[8];
  const float* bv = (const float*)d_in[9];
  const float* Wo = (const float*)d_in[10];
  const float* bo = (const float*)d_in[11];

  const size_t nx = (size_t)MROWS * DMODEL;
  const size_t nw = (size_t)DMODEL * DMODEL;
  u16* ws   = (u16*)d_ws;
  u16* xq_b = ws;
  u16* xk_b = xq_b + nx;
  u16* xv_b = xk_b + nx;
  u16* wq_b = xv_b + nx;
  u16* wk_b = wq_b + nw;
  u16* wv_b = wk_b + nw;
  u16* wo_b = wv_b + nw;
  u16* Qh   = wo_b + nw;
  u16* Kh   = Qh + nx;
  u16* Vt   = Kh + nx;
  u16* AO   = Vt + nx;  // total 64 MiB

  const int n4x = (int)(nx / 4), n4w = (int)(nw / 4);
  cvt_multi<<<dim3((n4x + 255) / 256, 3), 256, 0, stream>>>(
      x_q, x_k, x_v, nullptr, xq_b, xk_b, xv_b, nullptr, n4x);
  cvt_multi<<<dim3((n4w + 255) / 256, 4), 256, 0, stream>>>(
      Wq, Wk, Wv, Wo, wq_b, wk_b, wv_b, wo_b, n4w);

  gemm_qkv<<<dim3(MROWS / 128, DMODEL / 128, 3), 256, 0, stream>>>(
      xq_b, xk_b, xv_b, wq_b, wk_b, wv_b, bq, bk, bv, Qh, Kh, Vt);

  flash_attn<<<dim3(BATCH * NHEAD, TSEQ / 128), 512, 0, stream>>>(Qh, Kh, Vt, AO);

  gemm_o<<<dim3(MROWS / 128, DMODEL / 64), 256, 0, stream>>>(AO, wo_b, bo, (float*)d_out);
}